// Round 1
// baseline (2257.133 us; speedup 1.0000x reference)
//
#include <hip/hip_runtime.h>

#define NNODES 50000
#define NEDGES 800000
#define IN_F   256
#define HID_F  128
#define OUT_F  16
#define HOPS   30

// ---------------- graph setup kernels ----------------

__global__ void k_init_deg(int* __restrict__ deg, int n) {
    int i = blockIdx.x * blockDim.x + threadIdx.x;
    if (i < n) deg[i] = 1;  // self-loop
}

__global__ void k_count(const int* __restrict__ dst, int* __restrict__ deg, int e) {
    int i = blockIdx.x * blockDim.x + threadIdx.x;
    if (i < e) atomicAdd(&deg[dst[i]], 1);
}

__global__ void k_dinv(const int* __restrict__ deg, float* __restrict__ dinv, int n) {
    int i = blockIdx.x * blockDim.x + threadIdx.x;
    if (i < n) dinv[i] = rsqrtf((float)deg[i]);
}

// block-wise reduction of deg -> bsums[block]
__global__ void k_scan1(const int* __restrict__ deg, int* __restrict__ bsums, int n) {
    __shared__ int sh[256];
    int tid = threadIdx.x;
    int i = blockIdx.x * 256 + tid;
    sh[tid] = (i < n) ? deg[i] : 0;
    __syncthreads();
    for (int ofs = 128; ofs > 0; ofs >>= 1) {
        if (tid < ofs) sh[tid] += sh[tid + ofs];
        __syncthreads();
    }
    if (tid == 0) bsums[blockIdx.x] = sh[0];
}

// exclusive scan of bsums (tiny: nb<=256), also write row_ptr[n]=total
__global__ void k_scan2(int* __restrict__ bsums, int nb, int* __restrict__ rp, int n) {
    if (threadIdx.x == 0 && blockIdx.x == 0) {
        int run = 0;
        for (int b = 0; b < nb; ++b) { int t = bsums[b]; bsums[b] = run; run += t; }
        rp[n] = run;
    }
}

// intra-block exclusive scan + block offset -> row_ptr, cursor
__global__ void k_scan3(const int* __restrict__ deg, const int* __restrict__ bsums,
                        int* __restrict__ rp, int* __restrict__ cursor, int n) {
    __shared__ int sh[256];
    int tid = threadIdx.x;
    int i = blockIdx.x * 256 + tid;
    int v = (i < n) ? deg[i] : 0;
    sh[tid] = v;
    __syncthreads();
    for (int ofs = 1; ofs < 256; ofs <<= 1) {
        int t = 0;
        if (tid >= ofs) t = sh[tid - ofs];
        __syncthreads();
        sh[tid] += t;
        __syncthreads();
    }
    if (i < n) {
        int excl = sh[tid] - v + bsums[blockIdx.x];
        rp[i] = excl;
        cursor[i] = excl;
    }
}

__global__ void k_scatter(const int* __restrict__ src, const int* __restrict__ dst,
                          const float* __restrict__ dinv, int* __restrict__ cursor,
                          int* __restrict__ col, float* __restrict__ w, int e, int n) {
    int t = blockIdx.x * blockDim.x + threadIdx.x;
    if (t < e) {
        int s = src[t], d = dst[t];
        int pos = atomicAdd(&cursor[d], 1);
        col[pos] = s;
        w[pos] = dinv[s] * dinv[d];
    } else if (t < e + n) {
        int i = t - e;
        int pos = atomicAdd(&cursor[i], 1);
        col[pos] = i;
        w[pos] = dinv[i] * dinv[i];
    }
}

// ---------------- dense GEMM: C = (relu?)(A[M,K] @ W[K,NC] + b) ----------------

template<int K, int NC, bool RELU>
__global__ void k_gemm(const float* __restrict__ A, const float* __restrict__ W,
                       const float* __restrict__ b, float* __restrict__ C, int M) {
    constexpr int ROWS = 32;
    constexpr int NRG  = 256 / NC;   // row groups
    constexpr int RPT  = ROWS / NRG; // rows per thread
    __shared__ float sa[ROWS][K];
    int tid  = threadIdx.x;
    int row0 = blockIdx.x * ROWS;

    const float4* A4 = reinterpret_cast<const float4*>(A);
    constexpr int NV = ROWS * K / 4;
    for (int idx = tid; idx < NV; idx += 256) {
        int r  = idx / (K / 4);
        int c4 = idx % (K / 4);
        int gr = row0 + r;
        float4 v = (gr < M) ? A4[(size_t)gr * (K / 4) + c4]
                            : make_float4(0.f, 0.f, 0.f, 0.f);
        sa[r][c4 * 4 + 0] = v.x; sa[r][c4 * 4 + 1] = v.y;
        sa[r][c4 * 4 + 2] = v.z; sa[r][c4 * 4 + 3] = v.w;
    }
    __syncthreads();

    int col = tid % NC;
    int rg  = tid / NC;
    float acc[RPT];
#pragma unroll
    for (int j = 0; j < RPT; ++j) acc[j] = 0.f;

#pragma unroll 4
    for (int k = 0; k < K; ++k) {
        float wv = W[k * NC + col];
#pragma unroll
        for (int j = 0; j < RPT; ++j) acc[j] += sa[rg * RPT + j][k] * wv;
    }

    float bv = b[col];
#pragma unroll
    for (int j = 0; j < RPT; ++j) {
        int r = row0 + rg * RPT + j;
        if (r < M) {
            float v = acc[j] + bv;
            if (RELU) v = fmaxf(v, 0.f);
            C[(size_t)r * NC + col] = v;
        }
    }
}

// ---------------- propagation: out[d] = sum_e w[e] * H[col[e]] ----------------

template<bool RELU>
__global__ void k_prop128(const float* __restrict__ Hin, float* __restrict__ Hout,
                          const int* __restrict__ rp, const int* __restrict__ col,
                          const float* __restrict__ w, int n) {
    int g    = blockIdx.x * 8 + (threadIdx.x >> 5);  // node per 32-lane group
    int lane = threadIdx.x & 31;
    if (g >= n) return;
    int beg = rp[g], end = rp[g + 1];
    const float4* H4 = reinterpret_cast<const float4*>(Hin);
    float ax = 0.f, ay = 0.f, az = 0.f, aw = 0.f;
    for (int e = beg; e < end; ++e) {
        int s = col[e];
        float ww = w[e];
        float4 hv = H4[(size_t)s * 32 + lane];
        ax += ww * hv.x; ay += ww * hv.y; az += ww * hv.z; aw += ww * hv.w;
    }
    if (RELU) {
        ax = fmaxf(ax, 0.f); ay = fmaxf(ay, 0.f);
        az = fmaxf(az, 0.f); aw = fmaxf(aw, 0.f);
    }
    reinterpret_cast<float4*>(Hout)[(size_t)g * 32 + lane] = make_float4(ax, ay, az, aw);
}

__global__ void k_prop16(const float* __restrict__ Gin, float* __restrict__ Out,
                         const int* __restrict__ rp, const int* __restrict__ col,
                         const float* __restrict__ w, int n) {
    int g    = blockIdx.x * 64 + (threadIdx.x >> 2);  // node per 4-lane group
    int lane = threadIdx.x & 3;
    if (g >= n) return;
    int beg = rp[g], end = rp[g + 1];
    const float4* G4 = reinterpret_cast<const float4*>(Gin);
    float ax = 0.f, ay = 0.f, az = 0.f, aw = 0.f;
    for (int e = beg; e < end; ++e) {
        int s = col[e];
        float ww = w[e];
        float4 hv = G4[(size_t)s * 4 + lane];
        ax += ww * hv.x; ay += ww * hv.y; az += ww * hv.z; aw += ww * hv.w;
    }
    reinterpret_cast<float4*>(Out)[(size_t)g * 4 + lane] = make_float4(ax, ay, az, aw);
}

// ---------------- host launch ----------------

extern "C" void kernel_launch(void* const* d_in, const int* in_sizes, int n_in,
                              void* d_out, int out_size, void* d_ws, size_t ws_size,
                              hipStream_t stream) {
    const float* x  = (const float*)d_in[0];
    const float* W1 = (const float*)d_in[1];
    const float* b1 = (const float*)d_in[2];
    const float* W2 = (const float*)d_in[3];
    const float* b2 = (const float*)d_in[4];
    const float* Wc = (const float*)d_in[5];
    const float* bc = (const float*)d_in[6];
    const int*   ei = (const int*)d_in[7];
    const int* srcp = ei;
    const int* dstp = ei + NEDGES;
    float* out = (float*)d_out;

    char* p = (char*)d_ws;
    auto alloc = [&](size_t bytes) -> char* {
        char* r = p;
        p += (bytes + 255) & ~(size_t)255;
        return r;
    };
    int*   deg    = (int*)  alloc(NNODES * 4);
    float* dinv   = (float*)alloc(NNODES * 4);
    int*   rp     = (int*)  alloc((NNODES + 1) * 4);
    int*   cursor = (int*)  alloc(NNODES * 4);
    int*   bsums  = (int*)  alloc(256 * 4);
    int*   colA   = (int*)  alloc((size_t)(NEDGES + NNODES) * 4);
    float* wA     = (float*)alloc((size_t)(NEDGES + NNODES) * 4);
    float* H0     = (float*)alloc((size_t)NNODES * HID_F * 4);
    float* H1     = (float*)alloc((size_t)NNODES * HID_F * 4);
    float* G      = (float*)alloc((size_t)NNODES * OUT_F * 4);

    const int T = 256;
    auto nb = [](int n, int t) { return (n + t - 1) / t; };

    // graph norm + CSR build
    k_init_deg<<<nb(NNODES, T), T, 0, stream>>>(deg, NNODES);
    k_count<<<nb(NEDGES, T), T, 0, stream>>>(dstp, deg, NEDGES);
    k_dinv<<<nb(NNODES, T), T, 0, stream>>>(deg, dinv, NNODES);
    int NB = nb(NNODES, 256);
    k_scan1<<<NB, 256, 0, stream>>>(deg, bsums, NNODES);
    k_scan2<<<1, 1, 0, stream>>>(bsums, NB, rp, NNODES);
    k_scan3<<<NB, 256, 0, stream>>>(deg, bsums, rp, cursor, NNODES);
    k_scatter<<<nb(NEDGES + NNODES, T), T, 0, stream>>>(srcp, dstp, dinv, cursor,
                                                        colA, wA, NEDGES, NNODES);

    // dense part
    int GB = nb(NNODES, 32);
    k_gemm<IN_F, HID_F, true ><<<GB, 256, 0, stream>>>(x,  W1, b1, H0, NNODES);
    k_gemm<HID_F, HID_F, false><<<GB, 256, 0, stream>>>(H0, W2, b2, H1, NNODES);

    // 30 hops at width 128, relu fused into last hop
    float* cur = H1;
    float* nxt = H0;
    int PB = nb(NNODES, 8);
    for (int i = 0; i < HOPS; ++i) {
        if (i == HOPS - 1)
            k_prop128<true ><<<PB, 256, 0, stream>>>(cur, nxt, rp, colA, wA, NNODES);
        else
            k_prop128<false><<<PB, 256, 0, stream>>>(cur, nxt, rp, colA, wA, NNODES);
        float* t = cur; cur = nxt; nxt = t;
    }

    // classifier + final hop at width 16
    k_gemm<HID_F, OUT_F, false><<<GB, 256, 0, stream>>>(cur, Wc, bc, G, NNODES);
    k_prop16<<<nb(NNODES, 64), 256, 0, stream>>>(G, out, rp, colA, wA, NNODES);
}